// Round 1
// baseline (1568219.824 us; speedup 1.0000x reference)
//
#include <hip/hip_runtime.h>

// LSTM: B=64, T=1024, D=512, H=512. Gate order i,f,g,o.
// Phase A: xW GEMM, f16 MFMA, 128x128 tile, global_load_lds w16, XOR-swizzled LDS.
// Phase B: persistent scan, 64 WGs = 8 row-groups(8 rows) x 8 slices(64 units).
//   Cohort g = blocks == g (mod 8) -> one XCD (verified via HW_REG_XCC_ID handshake).
//   Fast path: write-through publish + sc0 polling (per-XCD L2, ~200cy RTT).
//   Safety net: every publish also agent-stores to IC; guard-tripped polls fall
//   back to agent loads, so mis-detection only costs speed, never correctness.

#define B_  64
#define T_  1024
#define D_  512
#define H_  512
#define G4H 2048

typedef _Float16 half8 __attribute__((ext_vector_type(8)));
typedef _Float16 half4 __attribute__((ext_vector_type(4)));
typedef float    f32x4 __attribute__((ext_vector_type(4)));
typedef unsigned long long ull;
typedef unsigned int u32;

static __device__ __forceinline__ float sigm(float x) { return 1.f / (1.f + __expf(-x)); }
static __device__ __forceinline__ float tanh_(float x) {
    float xc = fminf(fmaxf(x, -15.f), 15.f);
    float e  = __expf(2.f * xc);
    return (e - 1.f) / (e + 1.f);
}
static __device__ __forceinline__ float lo16f(unsigned u) {
    return (float)__builtin_bit_cast(_Float16, (unsigned short)(u & 0xffffu));
}
static __device__ __forceinline__ float hi16f(unsigned u) {
    return (float)__builtin_bit_cast(_Float16, (unsigned short)(u >> 16));
}
static __device__ __forceinline__ void gload_lds16(const _Float16* g, _Float16* l) {
    __builtin_amdgcn_global_load_lds((const __attribute__((address_space(1))) u32*)g,
                                     (__attribute__((address_space(3))) u32*)l, 16, 0, 0);
}

// ---------------- init: transpose-convert [512][2048] f32 -> [2048][512] f16
__global__ void trans_w(const float* __restrict__ W, _Float16* __restrict__ WT) {
    int idx = blockIdx.x * blockDim.x + threadIdx.x;
    int total = D_ * G4H;
    int stride = gridDim.x * blockDim.x;
    for (int i = idx; i < total; i += stride) {
        int k = i >> 11;
        int n = i & (G4H - 1);
        WT[(size_t)n * D_ + k] = (_Float16)W[i];
    }
}

// ---------------- init: x f32 -> f16
__global__ void conv_x(const float* __restrict__ x, _Float16* __restrict__ xh) {
    int idx = blockIdx.x * blockDim.x + threadIdx.x;
    int total = (B_ * T_ * D_) / 4;
    int stride = gridDim.x * blockDim.x;
    const f32x4* xi = (const f32x4*)x;
    half4* xo = (half4*)xh;
    for (int i = idx; i < total; i += stride) {
        f32x4 v = xi[i];
        xo[i] = (half4){(_Float16)v.x, (_Float16)v.y, (_Float16)v.z, (_Float16)v.w};
    }
}

__global__ void zero_buf(unsigned* __restrict__ p, int n) {
    int idx = blockIdx.x * blockDim.x + threadIdx.x;
    int stride = gridDim.x * blockDim.x;
    for (int i = idx; i < n; i += stride) p[i] = 0u;
}

// ---------------- phase A (fast): 128x128 tile, f16 A via precomputed xh
__global__ __launch_bounds__(256) void gemm_xw_f16(const _Float16* __restrict__ xh,
                                                   const _Float16* __restrict__ WkT,
                                                   const float* __restrict__ bias,
                                                   _Float16* __restrict__ xw, int tbase) {
    __shared__ _Float16 As[128 * 64];   // [row][64 k] f16, XOR-swizzled (byte ^= (row&7)<<4)
    __shared__ _Float16 Bs[128 * 64];
    const int tid  = threadIdx.x;
    const int lane = tid & 63;
    const int wave = tid >> 6;
    const int l15  = lane & 15;
    const int quad = lane >> 4;
    const int b     = blockIdx.z;
    const int n0    = blockIdx.x * 128;
    const int tloc0 = blockIdx.y * 128;

    const int srow = tid >> 3;   // 0..31 staging row within quarter
    const int sseg = tid & 7;    // 16B segment within row

    f32x4 acc[2][8];
#pragma unroll
    for (int rt = 0; rt < 2; ++rt)
#pragma unroll
        for (int ct = 0; ct < 8; ++ct) acc[rt][ct] = (f32x4){0.f, 0.f, 0.f, 0.f};

    const _Float16* abase = xh + ((size_t)b * T_ + tbase + tloc0) * D_;
    const _Float16* bbase = WkT + (size_t)n0 * D_;

    for (int kb = 0; kb < 8; ++kb) {
        __syncthreads();
#pragma unroll
        for (int q = 0; q < 4; ++q) {
            int row  = q * 32 + srow;
            int col2 = (sseg * 16) ^ ((row & 7) << 4);   // pre-swizzled global source
            _Float16* ldst = (_Float16*)((char*)As + q * 4096 + wave * 1024);
            gload_lds16(abase + (size_t)row * D_ + kb * 64 + (col2 >> 1), ldst);
            _Float16* ldstb = (_Float16*)((char*)Bs + q * 4096 + wave * 1024);
            gload_lds16(bbase + (size_t)row * D_ + kb * 64 + (col2 >> 1), ldstb);
        }
        __syncthreads();
#pragma unroll
        for (int ks = 0; ks < 2; ++ks) {
            half8 af[2];
#pragma unroll
            for (int rt = 0; rt < 2; ++rt) {
                int row = wave * 32 + rt * 16 + l15;
                int c2  = (ks * 64 + quad * 16) ^ ((row & 7) << 4);
                af[rt] = *(const half8*)&As[row * 64 + (c2 >> 1)];
            }
#pragma unroll
            for (int ct = 0; ct < 8; ++ct) {
                int brw = ct * 16 + l15;
                int c2  = (ks * 64 + quad * 16) ^ ((brw & 7) << 4);
                half8 bf = *(const half8*)&Bs[brw * 64 + (c2 >> 1)];
                acc[0][ct] = __builtin_amdgcn_mfma_f32_16x16x32_f16(af[0], bf, acc[0][ct], 0, 0, 0);
                acc[1][ct] = __builtin_amdgcn_mfma_f32_16x16x32_f16(af[1], bf, acc[1][ct], 0, 0, 0);
            }
        }
    }
#pragma unroll
    for (int ct = 0; ct < 8; ++ct) {
        int col = n0 + ct * 16 + l15;
        float bs = bias[col];
#pragma unroll
        for (int rt = 0; rt < 2; ++rt)
#pragma unroll
            for (int r = 0; r < 4; ++r) {
                int tt = tloc0 + wave * 32 + rt * 16 + quad * 4 + r;
                xw[((size_t)tt * B_ + b) * G4H + col] = (_Float16)(acc[rt][ct][r] + bs);
            }
    }
}

// ---------------- phase A (fallback, small ws): original 64x64 kernel, verbatim
__global__ __launch_bounds__(256) void gemm_xw_small(const float* __restrict__ x,
                                                     const _Float16* __restrict__ WkT,
                                                     const float* __restrict__ bias,
                                                     _Float16* __restrict__ xw,
                                                     int tbase) {
    __shared__ _Float16 As[64][40];
    __shared__ _Float16 Bst[64][40];
    const int tid  = threadIdx.x;
    const int lane = tid & 63;
    const int wave = tid >> 6;
    const int l15  = lane & 15;
    const int quad = lane >> 4;
    const int b     = blockIdx.z;
    const int n0    = blockIdx.x * 64;
    const int tloc0 = blockIdx.y * 64;

    const float* xbase = x + ((size_t)b * T_ + (tbase + tloc0)) * D_;
    f32x4 acc[4];
#pragma unroll
    for (int i = 0; i < 4; ++i) acc[i] = (f32x4){0.f, 0.f, 0.f, 0.f};

    const int ai = tid >> 2, ac = tid & 3;
    const int bn = tid >> 2, bq = tid & 3;

    for (int kb = 0; kb < 16; ++kb) {
        __syncthreads();
        const float* ap = xbase + (size_t)ai * D_ + kb * 32 + ac * 8;
        f32x4 av0 = *(const f32x4*)ap;
        f32x4 av1 = *(const f32x4*)(ap + 4);
        half8 ah = { (_Float16)av0.x, (_Float16)av0.y, (_Float16)av0.z, (_Float16)av0.w,
                     (_Float16)av1.x, (_Float16)av1.y, (_Float16)av1.z, (_Float16)av1.w };
        *(half8*)&As[ai][ac * 8] = ah;
        half8 bv = *(const half8*)(WkT + (size_t)(n0 + bn) * D_ + kb * 32 + bq * 8);
        *(half8*)&Bst[bn][bq * 8] = bv;
        __syncthreads();

        half8 afrag = *(const half8*)&As[16 * wave + l15][quad * 8];
#pragma unroll
        for (int nt = 0; nt < 4; ++nt) {
            half8 bfrag = *(const half8*)&Bst[nt * 16 + l15][quad * 8];
            acc[nt] = __builtin_amdgcn_mfma_f32_16x16x32_f16(afrag, bfrag, acc[nt], 0, 0, 0);
        }
    }
#pragma unroll
    for (int nt = 0; nt < 4; ++nt)
#pragma unroll
        for (int r = 0; r < 4; ++r) {
            int tt  = tloc0 + 16 * wave + quad * 4 + r;
            int col = n0 + nt * 16 + l15;
            xw[((size_t)tt * B_ + b) * G4H + col] = (_Float16)(acc[nt][r] + bias[col]);
        }
}

// ---------------- phase B: persistent scan, XCD-local cohorts
// 64 WGs x 256 thr. WG w: group g=w&7 (rows g*8..+7), slice s=w>>3 (units s*64..+63).
// Wave v = gate v, 4 column tiles of 16. bfrag: 4x16 half8 = 256 VGPR/thread.
// hbuf: 3 slots x [64][512] tagged dwords (lo16 = h f16, hi16 = step+1).
__global__ __launch_bounds__(256, 1) void lstm_scan(const _Float16* __restrict__ xw,
                                                    const _Float16* __restrict__ WrT,
                                                    unsigned* __restrict__ hbuf,
                                                    float* __restrict__ cio,
                                                    float* __restrict__ out,
                                                    unsigned* __restrict__ xcc_tbl,
                                                    int t0, int t1) {
    const int w    = blockIdx.x;
    const int g    = w & 7;
    const int s    = w >> 3;
    const int u0   = s * 64;
    const int tid  = threadIdx.x;
    const int lane = tid & 63;
    const int wave = tid >> 6;
    const int l15  = lane & 15;
    const int quad = lane >> 4;

    // ---- cohort co-location handshake (agent scope, epoch-tagged per launch)
    __shared__ int s_fast;
    if (tid == 0) {
        unsigned my;
        asm volatile("s_getreg_b32 %0, hwreg(HW_REG_XCC_ID)" : "=s"(my));
        unsigned ep = (unsigned)(t0 + 1);
        __hip_atomic_store(&xcc_tbl[w], (ep << 8) | (my & 0xffu),
                           __ATOMIC_RELAXED, __HIP_MEMORY_SCOPE_AGENT);
        int ok = 1;
        unsigned ref = 0xffffffffu;
        for (int sp = 0; sp < 8; ++sp) {
            unsigned e; int gd = 0;
            do {
                e = __hip_atomic_load(&xcc_tbl[g + 8 * sp], __ATOMIC_RELAXED,
                                      __HIP_MEMORY_SCOPE_AGENT);
            } while ((e >> 8) != ep && ++gd < (1 << 17));
            if ((e >> 8) != ep) { ok = 0; break; }
            unsigned xc = e & 0xffu;
            if (ref == 0xffffffffu) ref = xc;
            else if (xc != ref) { ok = 0; break; }
        }
        s_fast = ok;
    }

    // ---- B fragments in registers: wave v = gate v, 4 col tiles. 256 VGPRs.
    half8 bfrag[4][16];
#pragma unroll
    for (int ct = 0; ct < 4; ++ct) {
        const int col = wave * H_ + u0 + ct * 16 + l15;
        const _Float16* wp = WrT + (size_t)col * D_;
#pragma unroll
        for (int kt = 0; kt < 16; ++kt)
            bfrag[ct][kt] = *(const half8*)(wp + kt * 32 + quad * 8);
    }

    const int rho  = tid >> 5;        // batch-row in group (0..7)
    const int jj   = tid & 31;        // unit-pair in slice
    const int brow = g * 8 + rho;
    const int un0  = u0 + 2 * jj;
    float c0 = 0.f, c1 = 0.f;
    if (t0 != 0) {
        c0 = cio[(size_t)brow * H_ + un0];
        c1 = cio[(size_t)brow * H_ + un0 + 1];
    }

    __shared__ _Float16 hS[16][520];      // rows 8..15 stay zero (MFMA M-pad)
    __shared__ float    zS[8][4][66];     // z exchange

    for (int i = tid; i < 8 * 520; i += 256) ((_Float16*)&hS[8][0])[i] = (_Float16)0.f;
    __syncthreads();
    const bool fast = (s_fast != 0);

    const size_t slotSz = (size_t)B_ * H_;   // dwords per slot
    const int prow = tid >> 5;               // poll row (== rho)
    const int pcol = tid & 31;               // poll ull base

    for (int t = t0; t < t1; ++t) {
        // prefetch xw: 4 f16-pair dwords, one per gate
        const unsigned* xwd = (const unsigned*)(xw + ((size_t)(t - t0) * B_ + brow) * G4H);
        const int dbase = (u0 >> 1) + jj;
        unsigned xwi = xwd[0 * 256 + dbase];
        unsigned xwf = xwd[1 * 256 + dbase];
        unsigned xwg = xwd[2 * 256 + dbase];
        unsigned xwo = xwd[3 * 256 + dbase];

        if (t > 0) {
            const ull* src = (const ull*)(hbuf + (size_t)((t - 1) % 3) * slotSz)
                             + (size_t)brow * 256 + pcol;
            const unsigned tgt = (unsigned)(t & 0xffff);
            const ull expect = ((ull)tgt << 16) | ((ull)tgt << 48);
            ull v0, v1, v2, v3, v4, v5, v6, v7;
            if (fast) {
                int guard = 0;
                while (true) {
                    asm volatile(
                        "global_load_dwordx2 %0, %8, off offset:0 sc0\n\t"
                        "global_load_dwordx2 %1, %8, off offset:256 sc0\n\t"
                        "global_load_dwordx2 %2, %8, off offset:512 sc0\n\t"
                        "global_load_dwordx2 %3, %8, off offset:768 sc0\n\t"
                        "global_load_dwordx2 %4, %8, off offset:1024 sc0\n\t"
                        "global_load_dwordx2 %5, %8, off offset:1280 sc0\n\t"
                        "global_load_dwordx2 %6, %8, off offset:1536 sc0\n\t"
                        "global_load_dwordx2 %7, %8, off offset:1792 sc0\n\t"
                        "s_waitcnt vmcnt(0)"
                        : "=&v"(v0), "=&v"(v1), "=&v"(v2), "=&v"(v3),
                          "=&v"(v4), "=&v"(v5), "=&v"(v6), "=&v"(v7)
                        : "v"(src) : "memory");
                    ull diff = ((v0 ^ expect) | (v1 ^ expect) | (v2 ^ expect) | (v3 ^ expect)
                              | (v4 ^ expect) | (v5 ^ expect) | (v6 ^ expect) | (v7 ^ expect))
                              & 0xffff0000ffff0000ull;
                    if (diff == 0) break;
                    if (++guard > (1 << 13)) {
                        // safety: agent spins (dual-store guarantees an IC copy)
#define SPIN_K(vk, off_) { int gd = 0;                                              \
    while ((((vk) ^ expect) & 0xffff0000ffff0000ull) && ++gd < (1 << 16))           \
        (vk) = __hip_atomic_load(src + (off_), __ATOMIC_RELAXED,                    \
                                 __HIP_MEMORY_SCOPE_AGENT); }
                        SPIN_K(v0, 0)   SPIN_K(v1, 32)  SPIN_K(v2, 64)  SPIN_K(v3, 96)
                        SPIN_K(v4, 128) SPIN_K(v5, 160) SPIN_K(v6, 192) SPIN_K(v7, 224)
#undef SPIN_K
                        break;
                    }
                }
            } else {
                int guard = 0;
                while (true) {
                    v0 = __hip_atomic_load(src + 0,   __ATOMIC_RELAXED, __HIP_MEMORY_SCOPE_AGENT);
                    v1 = __hip_atomic_load(src + 32,  __ATOMIC_RELAXED, __HIP_MEMORY_SCOPE_AGENT);
                    v2 = __hip_atomic_load(src + 64,  __ATOMIC_RELAXED, __HIP_MEMORY_SCOPE_AGENT);
                    v3 = __hip_atomic_load(src + 96,  __ATOMIC_RELAXED, __HIP_MEMORY_SCOPE_AGENT);
                    v4 = __hip_atomic_load(src + 128, __ATOMIC_RELAXED, __HIP_MEMORY_SCOPE_AGENT);
                    v5 = __hip_atomic_load(src + 160, __ATOMIC_RELAXED, __HIP_MEMORY_SCOPE_AGENT);
                    v6 = __hip_atomic_load(src + 192, __ATOMIC_RELAXED, __HIP_MEMORY_SCOPE_AGENT);
                    v7 = __hip_atomic_load(src + 224, __ATOMIC_RELAXED, __HIP_MEMORY_SCOPE_AGENT);
                    ull diff = ((v0 ^ expect) | (v1 ^ expect) | (v2 ^ expect) | (v3 ^ expect)
                              | (v4 ^ expect) | (v5 ^ expect) | (v6 ^ expect) | (v7 ^ expect))
                              & 0xffff0000ffff0000ull;
                    if (diff == 0) break;
                    if (++guard > (1 << 14)) break;   // bailout: visible failure, not a hang
                }
            }
            // strip tags, pack 2 f16 -> dword, stage to LDS
            *(unsigned*)&hS[prow][2 * pcol + 0]   = (unsigned)(v0 & 0xffffu) | ((unsigned)(v0 >> 32) << 16);
            *(unsigned*)&hS[prow][2 * pcol + 64]  = (unsigned)(v1 & 0xffffu) | ((unsigned)(v1 >> 32) << 16);
            *(unsigned*)&hS[prow][2 * pcol + 128] = (unsigned)(v2 & 0xffffu) | ((unsigned)(v2 >> 32) << 16);
            *(unsigned*)&hS[prow][2 * pcol + 192] = (unsigned)(v3 & 0xffffu) | ((unsigned)(v3 >> 32) << 16);
            *(unsigned*)&hS[prow][2 * pcol + 256] = (unsigned)(v4 & 0xffffu) | ((unsigned)(v4 >> 32) << 16);
            *(unsigned*)&hS[prow][2 * pcol + 320] = (unsigned)(v5 & 0xffffu) | ((unsigned)(v5 >> 32) << 16);
            *(unsigned*)&hS[prow][2 * pcol + 384] = (unsigned)(v6 & 0xffffu) | ((unsigned)(v6 >> 32) << 16);
            *(unsigned*)&hS[prow][2 * pcol + 448] = (unsigned)(v7 & 0xffffu) | ((unsigned)(v7 >> 32) << 16);
        }
        __syncthreads();   // BARRIER1: hS staged (also protects hS vs prev-step readers)

        f32x4 a0 = {0.f, 0.f, 0.f, 0.f}, a1 = a0, a2 = a0, a3 = a0;
        if (t > 0) {
#pragma unroll
            for (int kt = 0; kt < 16; ++kt) {
                half8 af = *(const half8*)&hS[l15][kt * 32 + quad * 8];
                a0 = __builtin_amdgcn_mfma_f32_16x16x32_f16(af, bfrag[0][kt], a0, 0, 0, 0);
                a1 = __builtin_amdgcn_mfma_f32_16x16x32_f16(af, bfrag[1][kt], a1, 0, 0, 0);
                a2 = __builtin_amdgcn_mfma_f32_16x16x32_f16(af, bfrag[2][kt], a2, 0, 0, 0);
                a3 = __builtin_amdgcn_mfma_f32_16x16x32_f16(af, bfrag[3][kt], a3, 0, 0, 0);
            }
        }
        if (quad < 2) {
#pragma unroll
            for (int r = 0; r < 4; ++r) {
                int row = quad * 4 + r;
                zS[row][wave][0 * 16 + l15] = a0[r];
                zS[row][wave][1 * 16 + l15] = a1[r];
                zS[row][wave][2 * 16 + l15] = a2[r];
                zS[row][wave][3 * 16 + l15] = a3[r];
            }
        }
        __syncthreads();   // BARRIER2: zS ready

        float zi0 = zS[rho][0][2*jj] + lo16f(xwi), zi1 = zS[rho][0][2*jj+1] + hi16f(xwi);
        float zf0 = zS[rho][1][2*jj] + lo16f(xwf), zf1 = zS[rho][1][2*jj+1] + hi16f(xwf);
        float zg0 = zS[rho][2][2*jj] + lo16f(xwg), zg1 = zS[rho][2][2*jj+1] + hi16f(xwg);
        float zo0 = zS[rho][3][2*jj] + lo16f(xwo), zo1 = zS[rho][3][2*jj+1] + hi16f(xwo);

        c0 = sigm(zf0) * c0 + sigm(zi0) * tanh_(zg0);
        c1 = sigm(zf1) * c1 + sigm(zi1) * tanh_(zg1);
        float h0 = sigm(zo0) * tanh_(c0);
        float h1 = sigm(zo1) * tanh_(c1);

        // tagged publish, dual path: L2 write-through (fast consumers) + IC (safety/fallback)
        const unsigned tagw = ((unsigned)((t + 1) & 0xffff)) << 16;
        unsigned d0 = (unsigned)__builtin_bit_cast(unsigned short, (_Float16)h0) | tagw;
        unsigned d1 = (unsigned)__builtin_bit_cast(unsigned short, (_Float16)h1) | tagw;
        ull wv = (ull)d0 | ((ull)d1 << 32);
        ull* dst = (ull*)(hbuf + (size_t)(t % 3) * slotSz) + (size_t)brow * 256 + (un0 >> 1);
        __hip_atomic_store(dst, wv, __ATOMIC_RELAXED, __HIP_MEMORY_SCOPE_WORKGROUP);
        asm volatile("" ::: "memory");   // keep both stores
        __hip_atomic_store(dst, wv, __ATOMIC_RELAXED, __HIP_MEMORY_SCOPE_AGENT);

        if (t == T_ - 1) {
            out[(size_t)brow * H_ + un0]     = h0;
            out[(size_t)brow * H_ + un0 + 1] = h1;
        }
    }
    cio[(size_t)brow * H_ + un0]     = c0;
    cio[(size_t)brow * H_ + un0 + 1] = c1;
}

// ---------------- launch
extern "C" void kernel_launch(void* const* d_in, const int* in_sizes, int n_in,
                              void* d_out, int out_size, void* d_ws, size_t ws_size,
                              hipStream_t stream) {
    (void)in_sizes; (void)n_in;
    const float* x    = (const float*)d_in[0];
    const float* Wk   = (const float*)d_in[1];
    const float* Wr   = (const float*)d_in[2];
    const float* bias = (const float*)d_in[3];
    float* out = (float*)d_out;

    char* ws = (char*)d_ws;
    unsigned* xcc  = (unsigned*)ws;                               // 256 B (in first KB)
    _Float16* WkT  = (_Float16*)(ws + 1024);                      // 2 MB
    _Float16* WrT  = (_Float16*)(ws + 1024 + 2097152);            // 2 MB
    unsigned* hbuf = (unsigned*)(ws + 1024 + 2 * 2097152);        // 384 KB (3 slots)
    float*    cio  = (float*)(ws + 1024 + 2 * 2097152 + 393216);  // 128 KB
    const size_t fixed   = 1024 + 2 * 2097152 + 393216 + 131072;
    const size_t xhBytes = (size_t)B_ * T_ * D_ * 2;              // 64 MB
    const size_t perT    = (size_t)B_ * G4H * 2;                  // 256 KB per timestep

    size_t avail = (ws_size > fixed) ? ws_size - fixed : 0;
    bool use_xh = avail >= xhBytes + 128 * perT;
    _Float16* xh = (_Float16*)(ws + fixed);
    _Float16* xw = (_Float16*)(ws + fixed + (use_xh ? xhBytes : 0));

    int ct = 0;
    if (use_xh) {
        const int cands[4] = {1024, 512, 256, 128};
        size_t av2 = avail - xhBytes;
        for (int i = 0; i < 4; ++i)
            if ((size_t)cands[i] * perT <= av2) { ct = cands[i]; break; }
    } else {
        const int cands[5] = {1024, 512, 256, 128, 64};
        for (int i = 0; i < 5; ++i)
            if ((size_t)cands[i] * perT <= avail) { ct = cands[i]; break; }
    }
    if (ct == 0) {
        hipMemsetAsync(d_out, 0, (size_t)out_size * 4, stream);
        return;
    }

    zero_buf<<<96, 256, 0, stream>>>(hbuf, 3 * B_ * H_);
    zero_buf<<<1, 64, 0, stream>>>(xcc, 64);
    trans_w<<<512, 256, 0, stream>>>(Wk, WkT);
    trans_w<<<512, 256, 0, stream>>>(Wr, WrT);
    if (use_xh) conv_x<<<2048, 256, 0, stream>>>(x, xh);

    for (int t0 = 0; t0 < T_; t0 += ct) {
        if (use_xh)
            gemm_xw_f16<<<dim3(16, ct / 128, B_), 256, 0, stream>>>(xh, WkT, bias, xw, t0);
        else
            gemm_xw_small<<<dim3(32, ct / 64, B_), 256, 0, stream>>>(x, WkT, bias, xw, t0);
        lstm_scan<<<64, 256, 0, stream>>>(xw, WrT, hbuf, cio, out, xcc, t0, t0 + ct);
    }
}

// Round 3
// 5826.188 us; speedup vs baseline: 269.1674x; 269.1674x over previous
//
#include <hip/hip_runtime.h>

// LSTM: B=64, T=1024, D=512, H=512. Gate order i,f,g,o.
// Phase A: xW GEMM, f16 MFMA, 128x128 tile, global_load_lds w16, XOR-swizzled LDS.
// Phase B: persistent scan, 64 WGs = 8 row-groups(8 rows) x 8 slices(64 units).
//   Primary protocol: tag-in-data publish + agent-scope polling (proven).
//   Speculative: sc0 (L2-scope) polls with STICKY degrade — first guard trip
//   permanently switches the thread to agent loads (bounded ~100us worst case).
//   One barrier per step: per-wave gate tiling makes z-exchange intra-wave;
//   hS double-buffered so the staging barrier covers cross-step reuse.
//   Guards sized so rocprof-replay-poisoned runs stay bounded (~1s worst case).

#define B_  64
#define T_  1024
#define D_  512
#define H_  512
#define G4H 2048

typedef _Float16 half8 __attribute__((ext_vector_type(8)));
typedef _Float16 half4 __attribute__((ext_vector_type(4)));
typedef float    f32x4 __attribute__((ext_vector_type(4)));
typedef unsigned long long ull;
typedef unsigned int u32;

static __device__ __forceinline__ float sigm(float x) { return 1.f / (1.f + __expf(-x)); }
static __device__ __forceinline__ float tanh_(float x) {
    float xc = fminf(fmaxf(x, -15.f), 15.f);
    float e  = __expf(2.f * xc);
    return (e - 1.f) / (e + 1.f);
}
static __device__ __forceinline__ float lo16f(unsigned u) {
    return (float)__builtin_bit_cast(_Float16, (unsigned short)(u & 0xffffu));
}
static __device__ __forceinline__ float hi16f(unsigned u) {
    return (float)__builtin_bit_cast(_Float16, (unsigned short)(u >> 16));
}
static __device__ __forceinline__ void gload_lds16(const _Float16* g, _Float16* l) {
    __builtin_amdgcn_global_load_lds((const __attribute__((address_space(1))) u32*)g,
                                     (__attribute__((address_space(3))) u32*)l, 16, 0, 0);
}

// ---------------- init: transpose-convert [512][2048] f32 -> [2048][512] f16
__global__ void trans_w(const float* __restrict__ W, _Float16* __restrict__ WT) {
    int idx = blockIdx.x * blockDim.x + threadIdx.x;
    int total = D_ * G4H;
    int stride = gridDim.x * blockDim.x;
    for (int i = idx; i < total; i += stride) {
        int k = i >> 11;
        int n = i & (G4H - 1);
        WT[(size_t)n * D_ + k] = (_Float16)W[i];
    }
}

// ---------------- init: x f32 -> f16
__global__ void conv_x(const float* __restrict__ x, _Float16* __restrict__ xh) {
    int idx = blockIdx.x * blockDim.x + threadIdx.x;
    int total = (B_ * T_ * D_) / 4;
    int stride = gridDim.x * blockDim.x;
    const f32x4* xi = (const f32x4*)x;
    half4* xo = (half4*)xh;
    for (int i = idx; i < total; i += stride) {
        f32x4 v = xi[i];
        xo[i] = (half4){(_Float16)v.x, (_Float16)v.y, (_Float16)v.z, (_Float16)v.w};
    }
}

__global__ void zero_buf(unsigned* __restrict__ p, int n) {
    int idx = blockIdx.x * blockDim.x + threadIdx.x;
    int stride = gridDim.x * blockDim.x;
    for (int i = idx; i < n; i += stride) p[i] = 0u;
}

// ---------------- phase A (fast): 128x128 tile, f16 A via precomputed xh
__global__ __launch_bounds__(256) void gemm_xw_f16(const _Float16* __restrict__ xh,
                                                   const _Float16* __restrict__ WkT,
                                                   const float* __restrict__ bias,
                                                   _Float16* __restrict__ xw, int tbase) {
    __shared__ _Float16 As[128 * 64];   // [row][64 k] f16, XOR-swizzled (byte ^= (row&7)<<4)
    __shared__ _Float16 Bs[128 * 64];
    const int tid  = threadIdx.x;
    const int lane = tid & 63;
    const int wave = tid >> 6;
    const int l15  = lane & 15;
    const int quad = lane >> 4;
    const int b     = blockIdx.z;
    const int n0    = blockIdx.x * 128;
    const int tloc0 = blockIdx.y * 128;

    const int srow = tid >> 3;   // 0..31 staging row within quarter
    const int sseg = tid & 7;    // 16B segment within row

    f32x4 acc[2][8];
#pragma unroll
    for (int rt = 0; rt < 2; ++rt)
#pragma unroll
        for (int ct = 0; ct < 8; ++ct) acc[rt][ct] = (f32x4){0.f, 0.f, 0.f, 0.f};

    const _Float16* abase = xh + ((size_t)b * T_ + tbase + tloc0) * D_;
    const _Float16* bbase = WkT + (size_t)n0 * D_;

    for (int kb = 0; kb < 8; ++kb) {
        __syncthreads();
#pragma unroll
        for (int q = 0; q < 4; ++q) {
            int row  = q * 32 + srow;
            int col2 = (sseg * 16) ^ ((row & 7) << 4);   // pre-swizzled global source
            _Float16* ldst = (_Float16*)((char*)As + q * 4096 + wave * 1024);
            gload_lds16(abase + (size_t)row * D_ + kb * 64 + (col2 >> 1), ldst);
            _Float16* ldstb = (_Float16*)((char*)Bs + q * 4096 + wave * 1024);
            gload_lds16(bbase + (size_t)row * D_ + kb * 64 + (col2 >> 1), ldstb);
        }
        __syncthreads();
#pragma unroll
        for (int ks = 0; ks < 2; ++ks) {
            half8 af[2];
#pragma unroll
            for (int rt = 0; rt < 2; ++rt) {
                int row = wave * 32 + rt * 16 + l15;
                int c2  = (ks * 64 + quad * 16) ^ ((row & 7) << 4);
                af[rt] = *(const half8*)&As[row * 64 + (c2 >> 1)];
            }
#pragma unroll
            for (int ct = 0; ct < 8; ++ct) {
                int brw = ct * 16 + l15;
                int c2  = (ks * 64 + quad * 16) ^ ((brw & 7) << 4);
                half8 bf = *(const half8*)&Bs[brw * 64 + (c2 >> 1)];
                acc[0][ct] = __builtin_amdgcn_mfma_f32_16x16x32_f16(af[0], bf, acc[0][ct], 0, 0, 0);
                acc[1][ct] = __builtin_amdgcn_mfma_f32_16x16x32_f16(af[1], bf, acc[1][ct], 0, 0, 0);
            }
        }
    }
#pragma unroll
    for (int ct = 0; ct < 8; ++ct) {
        int col = n0 + ct * 16 + l15;
        float bs = bias[col];
#pragma unroll
        for (int rt = 0; rt < 2; ++rt)
#pragma unroll
            for (int r = 0; r < 4; ++r) {
                int tt = tloc0 + wave * 32 + rt * 16 + quad * 4 + r;
                xw[((size_t)tt * B_ + b) * G4H + col] = (_Float16)(acc[rt][ct][r] + bs);
            }
    }
}

// ---------------- phase A (fallback, small ws): 64x64 kernel
__global__ __launch_bounds__(256) void gemm_xw_small(const float* __restrict__ x,
                                                     const _Float16* __restrict__ WkT,
                                                     const float* __restrict__ bias,
                                                     _Float16* __restrict__ xw,
                                                     int tbase) {
    __shared__ _Float16 As[64][40];
    __shared__ _Float16 Bst[64][40];
    const int tid  = threadIdx.x;
    const int lane = tid & 63;
    const int wave = tid >> 6;
    const int l15  = lane & 15;
    const int quad = lane >> 4;
    const int b     = blockIdx.z;
    const int n0    = blockIdx.x * 64;
    const int tloc0 = blockIdx.y * 64;

    const float* xbase = x + ((size_t)b * T_ + (tbase + tloc0)) * D_;
    f32x4 acc[4];
#pragma unroll
    for (int i = 0; i < 4; ++i) acc[i] = (f32x4){0.f, 0.f, 0.f, 0.f};

    const int ai = tid >> 2, ac = tid & 3;
    const int bn = tid >> 2, bq = tid & 3;

    for (int kb = 0; kb < 16; ++kb) {
        __syncthreads();
        const float* ap = xbase + (size_t)ai * D_ + kb * 32 + ac * 8;
        f32x4 av0 = *(const f32x4*)ap;
        f32x4 av1 = *(const f32x4*)(ap + 4);
        half8 ah = { (_Float16)av0.x, (_Float16)av0.y, (_Float16)av0.z, (_Float16)av0.w,
                     (_Float16)av1.x, (_Float16)av1.y, (_Float16)av1.z, (_Float16)av1.w };
        *(half8*)&As[ai][ac * 8] = ah;
        half8 bv = *(const half8*)(WkT + (size_t)(n0 + bn) * D_ + kb * 32 + bq * 8);
        *(half8*)&Bst[bn][bq * 8] = bv;
        __syncthreads();

        half8 afrag = *(const half8*)&As[16 * wave + l15][quad * 8];
#pragma unroll
        for (int nt = 0; nt < 4; ++nt) {
            half8 bfrag = *(const half8*)&Bst[nt * 16 + l15][quad * 8];
            acc[nt] = __builtin_amdgcn_mfma_f32_16x16x32_f16(afrag, bfrag, acc[nt], 0, 0, 0);
        }
    }
#pragma unroll
    for (int nt = 0; nt < 4; ++nt)
#pragma unroll
        for (int r = 0; r < 4; ++r) {
            int tt  = tloc0 + 16 * wave + quad * 4 + r;
            int col = n0 + nt * 16 + l15;
            xw[((size_t)tt * B_ + b) * G4H + col] = (_Float16)(acc[nt][r] + bias[col]);
        }
}

// ---------------- phase B: persistent scan
// 64 WGs x 256 thr. WG w: group g=w&7 (rows g*8..+7), slice s=w>>3 (units s*64..+63).
// Wave v: units u0+v*16..+15, ALL 4 gates (z-exchange intra-wave, no barrier).
// hbuf: 3 slots x [64][512] tagged dwords (lo16 = h f16, hi16 = step+1).
__global__ __launch_bounds__(256, 1) void lstm_scan(const _Float16* __restrict__ xw,
                                                    const _Float16* __restrict__ WrT,
                                                    unsigned* __restrict__ hbuf,
                                                    float* __restrict__ cio,
                                                    float* __restrict__ out,
                                                    int t0, int t1) {
    const int w    = blockIdx.x;
    const int g    = w & 7;
    const int s    = w >> 3;
    const int u0   = s * 64;
    const int tid  = threadIdx.x;
    const int lane = tid & 63;
    const int wave = tid >> 6;
    const int l15  = lane & 15;
    const int quad = lane >> 4;

    // B fragments: wave v covers cols {q*512 + u0 + v*16 + l15 : q=0..3}. 256 VGPRs.
    half8 bfrag[4][16];
#pragma unroll
    for (int q = 0; q < 4; ++q) {
        const int col = q * H_ + u0 + wave * 16 + l15;
        const _Float16* wp = WrT + (size_t)col * D_;
#pragma unroll
        for (int kt = 0; kt < 16; ++kt)
            bfrag[q][kt] = *(const half8*)(wp + kt * 32 + quad * 8);
    }

    // poll mapping: thread covers row rho, ulls pcol+32k
    const int rho  = tid >> 5;
    const int pcol = tid & 31;
    // compute/publish mapping: wave-local (row8, unit-pair up)
    const int row8 = lane >> 3;
    const int up   = lane & 7;
    const int brow = g * 8 + row8;
    const int un0  = u0 + wave * 16 + 2 * up;

    float c0 = 0.f, c1 = 0.f;
    if (t0 != 0) {
        c0 = cio[(size_t)brow * H_ + un0];
        c1 = cio[(size_t)brow * H_ + un0 + 1];
    }

    __shared__ _Float16 hS[2][16][512];   // double-buffered, XOR-swizzled (byte^=(row&7)<<4)
    __shared__ float    zS[4][8][4][18];  // per-wave private z exchange

    // zero M-pad rows 8..15 of both buffers (read by MFMA, never staged)
    {
        u32* hz = (u32*)hS;
        for (int i = tid; i < 4096; i += 256) {
            int bsel = i >> 11;
            int off  = i & 2047;
            hz[bsel * 4096 + 2048 + off] = 0u;
        }
    }
    __syncthreads();

    const size_t slotSz = (size_t)B_ * H_;
    bool fastok = true;   // sticky: first sc0-guard trip degrades this thread to agent polls

    for (int t = t0; t < t1; ++t) {
        // xw prefetch: 4 f16-pair dwords, one per gate (issued before poll, consumed late)
        const unsigned* xwd = (const unsigned*)(xw + ((size_t)(t - t0) * B_ + brow) * G4H);
        const int dbase = ((u0 + wave * 16) >> 1) + up;
        unsigned xwi = xwd[0 * 256 + dbase];
        unsigned xwf = xwd[1 * 256 + dbase];
        unsigned xwg = xwd[2 * 256 + dbase];
        unsigned xwo = xwd[3 * 256 + dbase];

        if (t > 0) {
            const ull* src = (const ull*)(hbuf + (size_t)((t - 1) % 3) * slotSz)
                             + (size_t)(g * 8 + rho) * 256 + pcol;
            const unsigned tgt = (unsigned)(t & 0xffff);
            const ull expect = ((ull)tgt << 16) | ((ull)tgt << 48);
            ull v0 = 0, v1 = 0, v2 = 0, v3 = 0, v4 = 0, v5 = 0, v6 = 0, v7 = 0;
            bool got = false;
            if (fastok) {
                int guard = 0;
                while (true) {
                    asm volatile(
                        "global_load_dwordx2 %0, %8, off offset:0 sc0\n\t"
                        "global_load_dwordx2 %1, %8, off offset:256 sc0\n\t"
                        "global_load_dwordx2 %2, %8, off offset:512 sc0\n\t"
                        "global_load_dwordx2 %3, %8, off offset:768 sc0\n\t"
                        "global_load_dwordx2 %4, %8, off offset:1024 sc0\n\t"
                        "global_load_dwordx2 %5, %8, off offset:1280 sc0\n\t"
                        "global_load_dwordx2 %6, %8, off offset:1536 sc0\n\t"
                        "global_load_dwordx2 %7, %8, off offset:1792 sc0\n\t"
                        "s_waitcnt vmcnt(0)"
                        : "=&v"(v0), "=&v"(v1), "=&v"(v2), "=&v"(v3),
                          "=&v"(v4), "=&v"(v5), "=&v"(v6), "=&v"(v7)
                        : "v"(src) : "memory");
                    ull diff = ((v0 ^ expect) | (v1 ^ expect) | (v2 ^ expect) | (v3 ^ expect)
                              | (v4 ^ expect) | (v5 ^ expect) | (v6 ^ expect) | (v7 ^ expect))
                              & 0xffff0000ffff0000ull;
                    if (diff == 0) { got = true; break; }
                    if (++guard > 512) { fastok = false; break; }   // sticky degrade
                }
            }
            if (!got) {
                int guard = 0;
                while (true) {
                    v0 = __hip_atomic_load(src + 0,   __ATOMIC_RELAXED, __HIP_MEMORY_SCOPE_AGENT);
                    v1 = __hip_atomic_load(src + 32,  __ATOMIC_RELAXED, __HIP_MEMORY_SCOPE_AGENT);
                    v2 = __hip_atomic_load(src + 64,  __ATOMIC_RELAXED, __HIP_MEMORY_SCOPE_AGENT);
                    v3 = __hip_atomic_load(src + 96,  __ATOMIC_RELAXED, __HIP_MEMORY_SCOPE_AGENT);
                    v4 = __hip_atomic_load(src + 128, __ATOMIC_RELAXED, __HIP_MEMORY_SCOPE_AGENT);
                    v5 = __hip_atomic_load(src + 160, __ATOMIC_RELAXED, __HIP_MEMORY_SCOPE_AGENT);
                    v6 = __hip_atomic_load(src + 192, __ATOMIC_RELAXED, __HIP_MEMORY_SCOPE_AGENT);
                    v7 = __hip_atomic_load(src + 224, __ATOMIC_RELAXED, __HIP_MEMORY_SCOPE_AGENT);
                    ull diff = ((v0 ^ expect) | (v1 ^ expect) | (v2 ^ expect) | (v3 ^ expect)
                              | (v4 ^ expect) | (v5 ^ expect) | (v6 ^ expect) | (v7 ^ expect))
                              & 0xffff0000ffff0000ull;
                    if (diff == 0) break;
                    if (++guard > 4096) break;   // bailout: visible failure, not a hang
                }
            }
            // strip tags, pack 2 f16 -> dword, stage to hS[t&1] with XOR swizzle
            char* hrow = (char*)hS + (t & 1) * 16384 + rho * 1024;
#define STG(k_, vk_) *(unsigned*)(hrow + ((4 * pcol + 128 * (k_)) ^ (rho << 4))) = \
        (unsigned)((vk_) & 0xffffu) | ((unsigned)((vk_) >> 32) << 16);
            STG(0, v0) STG(1, v1) STG(2, v2) STG(3, v3)
            STG(4, v4) STG(5, v5) STG(6, v6) STG(7, v7)
#undef STG
        }
        __syncthreads();   // single barrier: hS[t&1] staged; also fences hS[t&1] reuse at t+2

        f32x4 a0 = {0.f, 0.f, 0.f, 0.f}, a1 = a0, a2 = a0, a3 = a0;
        if (t > 0) {
            const char* hbase = (const char*)hS + (t & 1) * 16384;
#pragma unroll
            for (int kt = 0; kt < 16; ++kt) {
                half8 af = *(const half8*)(hbase + l15 * 1024
                                           + ((kt * 64 + quad * 16) ^ ((l15 & 7) << 4)));
                a0 = __builtin_amdgcn_mfma_f32_16x16x32_f16(af, bfrag[0][kt], a0, 0, 0, 0);
                a1 = __builtin_amdgcn_mfma_f32_16x16x32_f16(af, bfrag[1][kt], a1, 0, 0, 0);
                a2 = __builtin_amdgcn_mfma_f32_16x16x32_f16(af, bfrag[2][kt], a2, 0, 0, 0);
                a3 = __builtin_amdgcn_mfma_f32_16x16x32_f16(af, bfrag[3][kt], a3, 0, 0, 0);
            }
        }
        // intra-wave z exchange (C layout: col=l15 -> unit, row=quad*4+r -> batch row)
        if (quad < 2) {
#pragma unroll
            for (int r = 0; r < 4; ++r) {
                int row = quad * 4 + r;
                zS[wave][row][0][l15] = a0[r];
                zS[wave][row][1][l15] = a1[r];
                zS[wave][row][2][l15] = a2[r];
                zS[wave][row][3][l15] = a3[r];
            }
        }
        // no barrier: producer and consumer are the same wave (lgkmcnt-ordered)
        float zi0 = zS[wave][row8][0][2*up] + lo16f(xwi), zi1 = zS[wave][row8][0][2*up+1] + hi16f(xwi);
        float zf0 = zS[wave][row8][1][2*up] + lo16f(xwf), zf1 = zS[wave][row8][1][2*up+1] + hi16f(xwf);
        float zg0 = zS[wave][row8][2][2*up] + lo16f(xwg), zg1 = zS[wave][row8][2][2*up+1] + hi16f(xwg);
        float zo0 = zS[wave][row8][3][2*up] + lo16f(xwo), zo1 = zS[wave][row8][3][2*up+1] + hi16f(xwo);

        c0 = sigm(zf0) * c0 + sigm(zi0) * tanh_(zg0);
        c1 = sigm(zf1) * c1 + sigm(zi1) * tanh_(zg1);
        float h0 = sigm(zo0) * tanh_(c0);
        float h1 = sigm(zo1) * tanh_(c1);

        // tagged publish, dual path: plain/WG store (L2, fast same-XCD consumers)
        // + agent store (IC, guaranteed-visible fallback)
        const unsigned tagw = ((unsigned)((t + 1) & 0xffff)) << 16;
        unsigned d0 = (unsigned)__builtin_bit_cast(unsigned short, (_Float16)h0) | tagw;
        unsigned d1 = (unsigned)__builtin_bit_cast(unsigned short, (_Float16)h1) | tagw;
        ull wv = (ull)d0 | ((ull)d1 << 32);
        ull* dst = (ull*)(hbuf + (size_t)(t % 3) * slotSz) + (size_t)brow * 256 + (un0 >> 1);
        __hip_atomic_store(dst, wv, __ATOMIC_RELAXED, __HIP_MEMORY_SCOPE_WORKGROUP);
        asm volatile("" ::: "memory");   // keep both stores, in order
        __hip_atomic_store(dst, wv, __ATOMIC_RELAXED, __HIP_MEMORY_SCOPE_AGENT);

        if (t == T_ - 1) {
            out[(size_t)brow * H_ + un0]     = h0;
            out[(size_t)brow * H_ + un0 + 1] = h1;
        }
    }
    cio[(size_t)brow * H_ + un0]     = c0;
    cio[(size_t)brow * H_ + un0 + 1] = c1;
}

// ---------------- launch
extern "C" void kernel_launch(void* const* d_in, const int* in_sizes, int n_in,
                              void* d_out, int out_size, void* d_ws, size_t ws_size,
                              hipStream_t stream) {
    (void)in_sizes; (void)n_in;
    const float* x    = (const float*)d_in[0];
    const float* Wk   = (const float*)d_in[1];
    const float* Wr   = (const float*)d_in[2];
    const float* bias = (const float*)d_in[3];
    float* out = (float*)d_out;

    char* ws = (char*)d_ws;
    _Float16* WkT  = (_Float16*)(ws + 1024);                      // 2 MB
    _Float16* WrT  = (_Float16*)(ws + 1024 + 2097152);            // 2 MB
    unsigned* hbuf = (unsigned*)(ws + 1024 + 2 * 2097152);        // 384 KB (3 slots)
    float*    cio  = (float*)(ws + 1024 + 2 * 2097152 + 393216);  // 128 KB
    const size_t fixed   = 1024 + 2 * 2097152 + 393216 + 131072;
    const size_t xhBytes = (size_t)B_ * T_ * D_ * 2;              // 64 MB
    const size_t perT    = (size_t)B_ * G4H * 2;                  // 256 KB per timestep

    size_t avail = (ws_size > fixed) ? ws_size - fixed : 0;
    bool use_xh = avail >= xhBytes + 128 * perT;
    _Float16* xh = (_Float16*)(ws + fixed);
    _Float16* xw = (_Float16*)(ws + fixed + (use_xh ? xhBytes : 0));

    int ct = 0;
    if (use_xh) {
        const int cands[4] = {1024, 512, 256, 128};
        size_t av2 = avail - xhBytes;
        for (int i = 0; i < 4; ++i)
            if ((size_t)cands[i] * perT <= av2) { ct = cands[i]; break; }
    } else {
        const int cands[5] = {1024, 512, 256, 128, 64};
        for (int i = 0; i < 5; ++i)
            if ((size_t)cands[i] * perT <= avail) { ct = cands[i]; break; }
    }
    if (ct == 0) {
        hipMemsetAsync(d_out, 0, (size_t)out_size * 4, stream);
        return;
    }

    zero_buf<<<96, 256, 0, stream>>>(hbuf, 3 * B_ * H_);
    trans_w<<<512, 256, 0, stream>>>(Wk, WkT);
    trans_w<<<512, 256, 0, stream>>>(Wr, WrT);
    if (use_xh) conv_x<<<2048, 256, 0, stream>>>(x, xh);

    for (int t0 = 0; t0 < T_; t0 += ct) {
        if (use_xh)
            gemm_xw_f16<<<dim3(16, ct / 128, B_), 256, 0, stream>>>(xh, WkT, bias, xw, t0);
        else
            gemm_xw_small<<<dim3(32, ct / 64, B_), 256, 0, stream>>>(x, WkT, bias, xw, t0);
        lstm_scan<<<64, 256, 0, stream>>>(xw, WrT, hbuf, cio, out, t0, t0 + ct);
    }
}